// Round 5
// baseline (183.690 us; speedup 1.0000x reference)
//
#include <hip/hip_runtime.h>
#include <math.h>

#define D_INNER 5120
#define DT_RANK 160
#define N_STATE 16
#define BATCH   256
#define KTOT    192               // 160 (dt_low) | 16 (B) | 16 (C)

// ---- K1 config: 256-thr blocks, 4 waves x 40-dd chunks, intra-block reduce ----
#define BGRP    8                 // batches per block
#define NBG     (BATCH / BGRP)    // 32
#define DDBLK   160               // dd per block (4 waves x 40)
#define NDDB    (D_INNER / DDBLK) // 32 -> SPLIT partials
#define SPLIT   32

// ---- K3 config: FUSED, 4 batches/block, grid (20,64)=1280 blocks ----
#define K3_BT   4

// ---- workspace layout (float offsets) ----
#define OFF_T     0
#define SZ_T      (BATCH * KTOT)                  // 49,152
#define OFF_P     (OFF_T + SZ_T)
#define SZ_P      (SPLIT * BATCH * KTOT)          // 1,572,864 (6.3 MB)
#define OFF_SBC   (OFF_P + SZ_P)                  // sbc[b] = sum_n T[b][160+n]*T[b][176+n]

// ---------------------------------------------------------------------------
// K1: projection GEMM partials (unchanged, ~10 us).
// ---------------------------------------------------------------------------
__global__ __launch_bounds__(256) void k1_gemm(const float* __restrict__ x,
                                               const float* __restrict__ Wdtlow,
                                               const float* __restrict__ WB,
                                               const float* __restrict__ WC,
                                               float* __restrict__ ws) {
    __shared__ float lds[4 * BGRP * KTOT];   // 6144 floats = 24 KB
    const int tid  = threadIdx.x;
    const int lane = tid & 63;
    const int wv   = tid >> 6;               // wave 0..3
    const int b0   = blockIdx.x * BGRP;
    const int ddB  = blockIdx.y * DDBLK;

    float* xs = lds;
    for (int j = tid; j < (BGRP * DDBLK) / 4; j += 256) {   // 320 float4
        int i  = j / (DDBLK / 4);
        int c4 = j % (DDBLK / 4);
        float4 v = *(const float4*)(x + (size_t)(b0 + i) * D_INNER + ddB + c4 * 4);
        *(float4*)(xs + i * DDBLK + c4 * 4) = v;
    }
    __syncthreads();

    const int dd0 = wv * 40;
    const float* p0 = Wdtlow + (size_t)(ddB + dd0) * DT_RANK + lane;
    const float* p1 = p0 + 64;
    const float* p2;
    int st2;
    if (lane < 32)      { p2 = p0 + 128;                                          st2 = DT_RANK; }
    else if (lane < 48) { p2 = WB + (size_t)(ddB + dd0) * N_STATE + (lane - 32);  st2 = N_STATE; }
    else                { p2 = WC + (size_t)(ddB + dd0) * N_STATE + (lane - 48);  st2 = N_STATE; }

    float acc0[BGRP], acc1[BGRP], acc2[BGRP];
#pragma unroll
    for (int i = 0; i < BGRP; ++i) { acc0[i] = 0.f; acc1[i] = 0.f; acc2[i] = 0.f; }

#pragma unroll 2
    for (int g = 0; g < 10; ++g) {           // 4 dd per group
        float w0[4], w1[4], w2[4];
#pragma unroll
        for (int u = 0; u < 4; ++u) {
            int dd = g * 4 + u;
            w0[u] = p0[(size_t)dd * DT_RANK];
            w1[u] = p1[(size_t)dd * DT_RANK];
            w2[u] = p2[(size_t)dd * st2];
        }
#pragma unroll
        for (int i = 0; i < BGRP; ++i) {
            float4 xv = *(const float4*)(xs + i * DDBLK + dd0 + g * 4);
            acc0[i] += xv.x * w0[0] + xv.y * w0[1] + xv.z * w0[2] + xv.w * w0[3];
            acc1[i] += xv.x * w1[0] + xv.y * w1[1] + xv.z * w1[2] + xv.w * w1[3];
            acc2[i] += xv.x * w2[0] + xv.y * w2[1] + xv.z * w2[2] + xv.w * w2[3];
        }
    }
    __syncthreads();

#pragma unroll
    for (int i = 0; i < BGRP; ++i) {
        float* r = lds + wv * (BGRP * KTOT) + i * KTOT;
        r[lane]       = acc0[i];
        r[lane + 64]  = acc1[i];
        r[lane + 128] = acc2[i];
    }
    __syncthreads();

    float* P = ws + OFF_P + (size_t)blockIdx.y * (BATCH * KTOT) + (size_t)b0 * KTOT;
#pragma unroll
    for (int r = 0; r < 6; ++r) {
        int idx = tid + r * 256;
        P[idx] = lds[idx] + lds[idx + 1536] + lds[idx + 3072] + lds[idx + 4608];
    }
}

// ---------------------------------------------------------------------------
// K2: reduce split-K partials -> T[256][192], plus hoisted sbc[b]. (unchanged)
// ---------------------------------------------------------------------------
__global__ __launch_bounds__(192) void k2_reduce(float* __restrict__ ws) {
    __shared__ float ts[KTOT];
    const int b   = blockIdx.x;
    const int col = threadIdx.x;
    const float* P = ws + OFF_P + (size_t)b * KTOT + col;
    float a = 0.f;
#pragma unroll
    for (int s = 0; s < SPLIT; ++s) a += P[(size_t)s * (BATCH * KTOT)];
    ws[OFF_T + b * KTOT + col] = a;
    ts[col] = a;
    __syncthreads();
    if (col == 0) {
        float s2 = 0.f;
#pragma unroll
        for (int n = 0; n < N_STATE; ++n) s2 += ts[160 + n] * ts[176 + n];
        ws[OFF_SBC + b] = s2;
    }
}

// ---------------------------------------------------------------------------
// K3: FUSED delta GEMM + softplus + scan.
// Round-5 change (one variable): issue the FULL 95MB HBM stream up front —
// all 4 h0 batches (16 dwordx4) + 4 x values — before the GEMM loop, so the
// entire stream is in flight under the 160-iter GEMM + exp-heavy scan.
// Round-4 only prefetched batches 0,1: batches 2,3 (42 MB) were issued from
// inside the scan with ~150cy of covering compute vs ~900cy HBM latency ->
// two nearly-exposed stalls per thread + bursty (phase-synced) HBM drain.
// Register budget: 64 (h0) + 16 (A) + 8 (acc/xv) + ~12 GEMM pipeline + ~15
// addr/temps ~= 115 -> __launch_bounds__(256,4), cap 128, no spill.
// Occupancy 20 -> 16 waves/CU, but 16 waves x ~17KB in flight >> 9.2 KB/CU
// Little's-law need for 6.3 TB/s; GEMM issue (6.4k cy/SIMD) unaffected.
// ---------------------------------------------------------------------------
__global__ __launch_bounds__(256, 4) void k3_fused(const float* __restrict__ Wdt,
                                                   const float* __restrict__ b_dt,
                                                   const float* __restrict__ x,
                                                   const float* __restrict__ A,
                                                   const float* __restrict__ Dv,
                                                   const float* __restrict__ h0,
                                                   const float* __restrict__ ws,
                                                   float* __restrict__ out) {
    const int tid = threadIdx.x;
    const int d   = blockIdx.x * 256 + tid;
    const int b0  = blockIdx.y * K3_BT;
    const float* T  = ws + OFF_T;
    const float* SB = ws + OFF_SBC;

    // ---- issue the ENTIRE HBM stream first: h0 batches 0..3, then x ----
    const float4* hb = (const float4*)(h0 + ((size_t)b0 * D_INNER + d) * N_STATE);
    const size_t  hstride = (size_t)D_INNER * 4;     // float4s per batch step

    float4 hA0 = hb[0],            hA1 = hb[1],            hA2 = hb[2],            hA3 = hb[3];
    float4 hB0 = hb[hstride + 0],  hB1 = hb[hstride + 1],  hB2 = hb[hstride + 2],  hB3 = hb[hstride + 3];
    float4 hC0 = hb[2*hstride + 0],hC1 = hb[2*hstride + 1],hC2 = hb[2*hstride + 2],hC3 = hb[2*hstride + 3];
    float4 hD0 = hb[3*hstride + 0],hD1 = hb[3*hstride + 1],hD2 = hb[3*hstride + 2],hD3 = hb[3*hstride + 3];

    float xv[K3_BT];
#pragma unroll
    for (int i = 0; i < K3_BT; ++i) xv[i] = x[(size_t)(b0 + i) * D_INNER + d];

    const float bdt = b_dt[d];
    const float Dd  = Dv[d];
    const float4* a4 = (const float4*)(A + (size_t)d * N_STATE);
    float4 a0 = a4[0], a1 = a4[1], a2 = a4[2], a3 = a4[3];

    // ---- delta pre-activation GEMM: acc[i] = T[b0+i][0..159] . Wdt[:,d] ----
    // T rows wave-uniform -> s_loads; Wdt k-major coalesced; Wdt (3.3 MB)
    // is L2-resident after first touch. unroll 8 (proven codegen).
    float acc[K3_BT] = {0.f, 0.f, 0.f, 0.f};
#pragma unroll 8
    for (int k = 0; k < DT_RANK; ++k) {
        float w = Wdt[(size_t)k * D_INNER + d];
#pragma unroll
        for (int i = 0; i < K3_BT; ++i)
            acc[i] += T[(size_t)(b0 + i) * KTOT + k] * w;
    }

    // ---- scan over 4 batches; all h0 already in registers ----
#define SCAN_BATCH(i, H0, H1, H2, H3)                                         \
    {                                                                         \
        const int b = b0 + (i);                                               \
        const float* Tb = T + (size_t)b * KTOT;       /* uniform -> s_load */ \
        float v     = acc[i] + bdt;                                           \
        float delta = (v > 20.f) ? v : log1pf(__expf(v));                     \
        float sbc   = SB[b];                                                  \
        float y0, y1, y2, y3;                                                 \
        y0  = __expf(delta * a0.x) * H0.x * Tb[176 + 0];                      \
        y0 += __expf(delta * a0.y) * H0.y * Tb[176 + 1];                      \
        y0 += __expf(delta * a0.z) * H0.z * Tb[176 + 2];                      \
        y0 += __expf(delta * a0.w) * H0.w * Tb[176 + 3];                      \
        y1  = __expf(delta * a1.x) * H1.x * Tb[176 + 4];                      \
        y1 += __expf(delta * a1.y) * H1.y * Tb[176 + 5];                      \
        y1 += __expf(delta * a1.z) * H1.z * Tb[176 + 6];                      \
        y1 += __expf(delta * a1.w) * H1.w * Tb[176 + 7];                      \
        y2  = __expf(delta * a2.x) * H2.x * Tb[176 + 8];                      \
        y2 += __expf(delta * a2.y) * H2.y * Tb[176 + 9];                      \
        y2 += __expf(delta * a2.z) * H2.z * Tb[176 + 10];                     \
        y2 += __expf(delta * a2.w) * H2.w * Tb[176 + 11];                     \
        y3  = __expf(delta * a3.x) * H3.x * Tb[176 + 12];                     \
        y3 += __expf(delta * a3.y) * H3.y * Tb[176 + 13];                     \
        y3 += __expf(delta * a3.z) * H3.z * Tb[176 + 14];                     \
        y3 += __expf(delta * a3.w) * H3.w * Tb[176 + 15];                     \
        out[(size_t)b * D_INNER + d] = xv[i] * (Dd + delta * sbc)             \
                                     + ((y0 + y1) + (y2 + y3));               \
    }

    SCAN_BATCH(0, hA0, hA1, hA2, hA3)
    SCAN_BATCH(1, hB0, hB1, hB2, hB3)
    SCAN_BATCH(2, hC0, hC1, hC2, hC3)
    SCAN_BATCH(3, hD0, hD1, hD2, hD3)
#undef SCAN_BATCH
}

// ---------------------------------------------------------------------------
extern "C" void kernel_launch(void* const* d_in, const int* in_sizes, int n_in,
                              void* d_out, int out_size, void* d_ws, size_t ws_size,
                              hipStream_t stream) {
    const float* x      = (const float*)d_in[0];
    const float* Wdtlow = (const float*)d_in[1];
    const float* Wdt    = (const float*)d_in[2];
    const float* bdt    = (const float*)d_in[3];
    const float* WB     = (const float*)d_in[4];
    const float* WC     = (const float*)d_in[5];
    const float* A      = (const float*)d_in[6];
    const float* Dv     = (const float*)d_in[7];
    const float* h0     = (const float*)d_in[8];
    float* ws  = (float*)d_ws;
    float* out = (float*)d_out;

    // K1: projection GEMM partials (1024 blocks, unchanged)
    hipLaunchKernelGGL(k1_gemm, dim3(NBG, NDDB), dim3(256), 0, stream,
                       x, Wdtlow, WB, WC, ws);
    // K2: reduce partials -> T[256][192] + sbc[256]
    hipLaunchKernelGGL(k2_reduce, dim3(BATCH), dim3(192), 0, stream, ws);
    // K3: fused delta GEMM + scan, BT=4, grid (20,64)=1280 blocks
    hipLaunchKernelGGL(k3_fused, dim3(D_INNER / 256, BATCH / K3_BT), dim3(256),
                       0, stream, Wdt, bdt, x, A, Dv, h0, ws, out);
}

// Round 6
// 183.527 us; speedup vs baseline: 1.0009x; 1.0009x over previous
//
#include <hip/hip_runtime.h>
#include <math.h>

#define D_INNER 5120
#define DT_RANK 160
#define N_STATE 16
#define BATCH   256
#define KTOT    192               // 160 (dt_low) | 16 (B) | 16 (C)

// ---- K1 config: 256-thr blocks, 4 waves x 40-dd chunks, intra-block reduce ----
#define BGRP    8                 // batches per block
#define NBG     (BATCH / BGRP)    // 32
#define DDBLK   160               // dd per block (4 waves x 40)
#define NDDB    (D_INNER / DDBLK) // 32 -> SPLIT partials
#define SPLIT   32

// ---- K3 config: FUSED, 2 batches/block, grid (20,128)=2560 blocks ----
#define K3_BT   2

// ---- workspace layout (float offsets) ----
#define OFF_T     0
#define SZ_T      (BATCH * KTOT)                  // 49,152
#define OFF_P     (OFF_T + SZ_T)
#define SZ_P      (SPLIT * BATCH * KTOT)          // 1,572,864 (6.3 MB)
#define OFF_SBC   (OFF_P + SZ_P)                  // sbc[b] = sum_n T[b][160+n]*T[b][176+n]

// ---------------------------------------------------------------------------
// K1: projection GEMM partials (unchanged, ~10 us).
// ---------------------------------------------------------------------------
__global__ __launch_bounds__(256) void k1_gemm(const float* __restrict__ x,
                                               const float* __restrict__ Wdtlow,
                                               const float* __restrict__ WB,
                                               const float* __restrict__ WC,
                                               float* __restrict__ ws) {
    __shared__ float lds[4 * BGRP * KTOT];   // 6144 floats = 24 KB
    const int tid  = threadIdx.x;
    const int lane = tid & 63;
    const int wv   = tid >> 6;               // wave 0..3
    const int b0   = blockIdx.x * BGRP;
    const int ddB  = blockIdx.y * DDBLK;

    float* xs = lds;
    for (int j = tid; j < (BGRP * DDBLK) / 4; j += 256) {   // 320 float4
        int i  = j / (DDBLK / 4);
        int c4 = j % (DDBLK / 4);
        float4 v = *(const float4*)(x + (size_t)(b0 + i) * D_INNER + ddB + c4 * 4);
        *(float4*)(xs + i * DDBLK + c4 * 4) = v;
    }
    __syncthreads();

    const int dd0 = wv * 40;
    const float* p0 = Wdtlow + (size_t)(ddB + dd0) * DT_RANK + lane;
    const float* p1 = p0 + 64;
    const float* p2;
    int st2;
    if (lane < 32)      { p2 = p0 + 128;                                          st2 = DT_RANK; }
    else if (lane < 48) { p2 = WB + (size_t)(ddB + dd0) * N_STATE + (lane - 32);  st2 = N_STATE; }
    else                { p2 = WC + (size_t)(ddB + dd0) * N_STATE + (lane - 48);  st2 = N_STATE; }

    float acc0[BGRP], acc1[BGRP], acc2[BGRP];
#pragma unroll
    for (int i = 0; i < BGRP; ++i) { acc0[i] = 0.f; acc1[i] = 0.f; acc2[i] = 0.f; }

#pragma unroll 2
    for (int g = 0; g < 10; ++g) {           // 4 dd per group
        float w0[4], w1[4], w2[4];
#pragma unroll
        for (int u = 0; u < 4; ++u) {
            int dd = g * 4 + u;
            w0[u] = p0[(size_t)dd * DT_RANK];
            w1[u] = p1[(size_t)dd * DT_RANK];
            w2[u] = p2[(size_t)dd * st2];
        }
#pragma unroll
        for (int i = 0; i < BGRP; ++i) {
            float4 xv = *(const float4*)(xs + i * DDBLK + dd0 + g * 4);
            acc0[i] += xv.x * w0[0] + xv.y * w0[1] + xv.z * w0[2] + xv.w * w0[3];
            acc1[i] += xv.x * w1[0] + xv.y * w1[1] + xv.z * w1[2] + xv.w * w1[3];
            acc2[i] += xv.x * w2[0] + xv.y * w2[1] + xv.z * w2[2] + xv.w * w2[3];
        }
    }
    __syncthreads();

#pragma unroll
    for (int i = 0; i < BGRP; ++i) {
        float* r = lds + wv * (BGRP * KTOT) + i * KTOT;
        r[lane]       = acc0[i];
        r[lane + 64]  = acc1[i];
        r[lane + 128] = acc2[i];
    }
    __syncthreads();

    float* P = ws + OFF_P + (size_t)blockIdx.y * (BATCH * KTOT) + (size_t)b0 * KTOT;
#pragma unroll
    for (int r = 0; r < 6; ++r) {
        int idx = tid + r * 256;
        P[idx] = lds[idx] + lds[idx + 1536] + lds[idx + 3072] + lds[idx + 4608];
    }
}

// ---------------------------------------------------------------------------
// K2: reduce split-K partials -> T[256][192], plus hoisted sbc[b]. (unchanged)
// ---------------------------------------------------------------------------
__global__ __launch_bounds__(192) void k2_reduce(float* __restrict__ ws) {
    __shared__ float ts[KTOT];
    const int b   = blockIdx.x;
    const int col = threadIdx.x;
    const float* P = ws + OFF_P + (size_t)b * KTOT + col;
    float a = 0.f;
#pragma unroll
    for (int s = 0; s < SPLIT; ++s) a += P[(size_t)s * (BATCH * KTOT)];
    ws[OFF_T + b * KTOT + col] = a;
    ts[col] = a;
    __syncthreads();
    if (col == 0) {
        float s2 = 0.f;
#pragma unroll
        for (int n = 0; n < N_STATE; ++n) s2 += ts[160 + n] * ts[176 + n];
        ws[OFF_SBC + b] = s2;
    }
}

// ---------------------------------------------------------------------------
// K3: FUSED delta GEMM + softplus + scan — OCCUPANCY round.
// Diagnosis (3 profiled rounds of this family): HBM 13%, VALUBusy 22%,
// Occupancy 34% -> latency-bound with too few resident waves. BT=4's grid
// (1280 blocks = 5 blocks/CU) structurally caps residency at 20 waves/CU,
// and the compiler SINKS deep per-thread prefetches anyway (round 5:
// VGPR_Count=56 proves the 16-float4 prefetch never existed in the binary).
// Fix: BT=2 -> grid (20,128)=2560 blocks (10 blocks/CU), per-thread state
// halved (8 float4 h0 + 2 acc, ~75 VGPR) -> __launch_bounds__(256,6)
// (cap 85) gives 6 blocks/CU = 24 waves/CU RESIDENT (2.2x measured 11).
// Costs: Wdt L2 traffic 210->420 MB (~12 us of 34.5 TB/s L2 BW, overlapped);
// total FMA count invariant; h0/x/out traffic invariant. FETCH_SIZE showed
// only ~50 MB reaches HBM (L3 serves ~half of h0) -> HBM floor ~9 us.
// Known-bad avoided: (256,8) regalloc collapse (r3), residency/grid
// mismatch (r5), >2-batch register prefetch (r5, compiler sinks it).
// ---------------------------------------------------------------------------
__global__ __launch_bounds__(256, 6) void k3_fused(const float* __restrict__ Wdt,
                                                   const float* __restrict__ b_dt,
                                                   const float* __restrict__ x,
                                                   const float* __restrict__ A,
                                                   const float* __restrict__ Dv,
                                                   const float* __restrict__ h0,
                                                   const float* __restrict__ ws,
                                                   float* __restrict__ out) {
    const int tid = threadIdx.x;
    const int d   = blockIdx.x * 256 + tid;
    const int b0  = blockIdx.y * K3_BT;
    const float* T  = ws + OFF_T;
    const float* SB = ws + OFF_SBC;

    // ---- issue h0 (both batches) + x first; GEMM covers their latency ----
    const float4* hbA = (const float4*)(h0 + ((size_t)b0 * D_INNER + d) * N_STATE);
    const float4* hbB = (const float4*)(h0 + ((size_t)(b0 + 1) * D_INNER + d) * N_STATE);
    float4 hA0 = hbA[0], hA1 = hbA[1], hA2 = hbA[2], hA3 = hbA[3];
    float4 hB0 = hbB[0], hB1 = hbB[1], hB2 = hbB[2], hB3 = hbB[3];

    float xvA = x[(size_t)b0 * D_INNER + d];
    float xvB = x[(size_t)(b0 + 1) * D_INNER + d];

    const float bdt = b_dt[d];
    const float Dd  = Dv[d];
    const float4* a4 = (const float4*)(A + (size_t)d * N_STATE);
    float4 a0 = a4[0], a1 = a4[1], a2 = a4[2], a3 = a4[3];

    // ---- delta pre-activation GEMM: acc = T[b][0..159] . Wdt[:,d] ----
    // T rows wave-uniform -> s_loads; Wdt k-major coalesced, L2-resident.
    const float* tA = T + (size_t)b0 * KTOT;
    const float* tB = tA + KTOT;
    float accA = 0.f, accB = 0.f;
#pragma unroll 8
    for (int k = 0; k < DT_RANK; ++k) {
        float w = Wdt[(size_t)k * D_INNER + d];
        accA += tA[k] * w;
        accB += tB[k] * w;
    }

    // ---- scan: batch A then batch B (h0 already in registers) ----
#define SCAN_BATCH(ACC, XV, BIDX, TB, H0, H1, H2, H3)                         \
    {                                                                         \
        float v     = (ACC) + bdt;                                            \
        float delta = (v > 20.f) ? v : log1pf(__expf(v));                     \
        float sbc   = SB[BIDX];                                               \
        float y0, y1, y2, y3;                                                 \
        y0  = __expf(delta * a0.x) * H0.x * (TB)[176 + 0];                    \
        y0 += __expf(delta * a0.y) * H0.y * (TB)[176 + 1];                    \
        y0 += __expf(delta * a0.z) * H0.z * (TB)[176 + 2];                    \
        y0 += __expf(delta * a0.w) * H0.w * (TB)[176 + 3];                    \
        y1  = __expf(delta * a1.x) * H1.x * (TB)[176 + 4];                    \
        y1 += __expf(delta * a1.y) * H1.y * (TB)[176 + 5];                    \
        y1 += __expf(delta * a1.z) * H1.z * (TB)[176 + 6];                    \
        y1 += __expf(delta * a1.w) * H1.w * (TB)[176 + 7];                    \
        y2  = __expf(delta * a2.x) * H2.x * (TB)[176 + 8];                    \
        y2 += __expf(delta * a2.y) * H2.y * (TB)[176 + 9];                    \
        y2 += __expf(delta * a2.z) * H2.z * (TB)[176 + 10];                   \
        y2 += __expf(delta * a2.w) * H2.w * (TB)[176 + 11];                   \
        y3  = __expf(delta * a3.x) * H3.x * (TB)[176 + 12];                   \
        y3 += __expf(delta * a3.y) * H3.y * (TB)[176 + 13];                   \
        y3 += __expf(delta * a3.z) * H3.z * (TB)[176 + 14];                   \
        y3 += __expf(delta * a3.w) * H3.w * (TB)[176 + 15];                   \
        out[(size_t)(BIDX) * D_INNER + d] = (XV) * (Dd + delta * sbc)         \
                                          + ((y0 + y1) + (y2 + y3));          \
    }

    SCAN_BATCH(accA, xvA, b0,     tA, hA0, hA1, hA2, hA3)
    SCAN_BATCH(accB, xvB, b0 + 1, tB, hB0, hB1, hB2, hB3)
#undef SCAN_BATCH
}

// ---------------------------------------------------------------------------
extern "C" void kernel_launch(void* const* d_in, const int* in_sizes, int n_in,
                              void* d_out, int out_size, void* d_ws, size_t ws_size,
                              hipStream_t stream) {
    const float* x      = (const float*)d_in[0];
    const float* Wdtlow = (const float*)d_in[1];
    const float* Wdt    = (const float*)d_in[2];
    const float* bdt    = (const float*)d_in[3];
    const float* WB     = (const float*)d_in[4];
    const float* WC     = (const float*)d_in[5];
    const float* A      = (const float*)d_in[6];
    const float* Dv     = (const float*)d_in[7];
    const float* h0     = (const float*)d_in[8];
    float* ws  = (float*)d_ws;
    float* out = (float*)d_out;

    // K1: projection GEMM partials (1024 blocks, unchanged)
    hipLaunchKernelGGL(k1_gemm, dim3(NBG, NDDB), dim3(256), 0, stream,
                       x, Wdtlow, WB, WC, ws);
    // K2: reduce partials -> T[256][192] + sbc[256]
    hipLaunchKernelGGL(k2_reduce, dim3(BATCH), dim3(192), 0, stream, ws);
    // K3: fused delta GEMM + scan, BT=2, grid (20,128)=2560 blocks
    hipLaunchKernelGGL(k3_fused, dim3(D_INNER / 256, BATCH / K3_BT), dim3(256),
                       0, stream, Wdt, bdt, x, A, Dv, h0, ws, out);
}